// Round 5
// baseline (486.916 us; speedup 1.0000x reference)
//
#include <hip/hip_runtime.h>
#include <math.h>

typedef unsigned short u16;
typedef __attribute__((ext_vector_type(4))) float f32x4;
typedef __bf16 bf16x8 __attribute__((ext_vector_type(8)));

#define NTOK 8192
#define DDIM 1024
#define NEXP 7
#define CAPC 2574      /* int(8192*2/7*1.1) */
#define CPAD 2688      /* 21*128 */
#define EBLK 1176      /* 7 experts * 21 mblk * 8 nblk */
#define TBLK 1688      /* + 64*8 shared blocks */

__device__ inline float bf2f(u16 u) {
    union { unsigned int i; float f; } c; c.i = ((unsigned int)u) << 16; return c.f;
}
__device__ inline u16 f2bf(float f) {
    union { float f; unsigned int i; } c; c.f = f;
    unsigned int u = c.i;
    unsigned int r = (u + 0x7fffu + ((u >> 16) & 1u)) >> 16;
    return (u16)r;
}

__device__ inline void gl2lds16(const u16* g, const u16* l) {
    __builtin_amdgcn_global_load_lds(
        (const __attribute__((address_space(1))) unsigned int*)g,
        (__attribute__((address_space(3))) unsigned int*)l, 16, 0, 0);
}

// ---------------- guard: zero the output (ws_size-too-small diagnostic) ----------------
__global__ void k_zero(float* out, long n) {
    long i = (long)blockIdx.x * 256 + threadIdx.x;
    long stride = (long)gridDim.x * 256;
    for (; i < n; i += stride) out[i] = 0.f;
}

// ---------------- prep: fp32 x -> bf16 xb, plus zrow + slot_token init ----------------
__global__ void k_prep(const float* __restrict__ x, u16* __restrict__ xb,
                       int* __restrict__ slot_token, u16* __restrict__ zrow) {
    int gid = blockIdx.x * 256 + threadIdx.x;
    int i = gid * 8;
    float4 a = *(const float4*)(x + i);
    float4 b = *(const float4*)(x + i + 4);
    ushort4 o0; o0.x = f2bf(a.x); o0.y = f2bf(a.y); o0.z = f2bf(a.z); o0.w = f2bf(a.w);
    ushort4 o1; o1.x = f2bf(b.x); o1.y = f2bf(b.y); o1.z = f2bf(b.z); o1.w = f2bf(b.w);
    *(ushort4*)(xb + i) = o0;
    *(ushort4*)(xb + i + 4) = o1;
    if (gid < DDIM) zrow[gid] = 0;
    if (gid < NEXP * CPAD) slot_token[gid] = NTOK;
}

// ---------------- weight transpose: fp32 [K][N] -> bf16 [N][K] (one phase) ----------------
// grid (4,128,8): z<7 -> expert z of srcE; z==7 -> srcS (shared)
__global__ void k_transpose(const float* __restrict__ srcE, const float* __restrict__ srcS,
                            u16* __restrict__ Wt, u16* __restrict__ Wst) {
    int z = blockIdx.z;
    const float* src; u16* dst;
    if (z < 7) { src = srcE + (long)z * 1048576; dst = Wt + (long)z * 1048576; }
    else       { src = srcS;                     dst = Wst; }
    int n = blockIdx.x * 256 + threadIdx.x;
    int k0 = blockIdx.y * 8;
    u16 v[8];
#pragma unroll
    for (int j = 0; j < 8; ++j) v[j] = f2bf(src[(long)(k0 + j) * 1024 + n]);
    ushort4 a; a.x = v[0]; a.y = v[1]; a.z = v[2]; a.w = v[3];
    ushort4 b; b.x = v[4]; b.y = v[5]; b.z = v[6]; b.w = v[7];
    *(ushort4*)(dst + (long)n * 1024 + k0) = a;
    *(ushort4*)(dst + (long)n * 1024 + k0 + 4) = b;
}

// ---------------- router: fp64 logits, softplus-noise, top-2, softmax ----------------
// 512 blocks x 256 thr; each wave handles 4 tokens serially (weight load amortized)
__global__ __launch_bounds__(256) void k_router(
    const float* __restrict__ x, const float* __restrict__ noise,
    const float* __restrict__ Wr, const float* __restrict__ br,
    const float* __restrict__ Wn, const float* __restrict__ bn,
    int* __restrict__ idx0, int* __restrict__ idx1,
    float* __restrict__ p0, float* __restrict__ p1) {
    __shared__ float swr[7168];
    __shared__ float swn[7168];
    int tid = threadIdx.x;
    for (int i = tid; i < 7168; i += 256) { swr[i] = Wr[i]; swn[i] = Wn[i]; }
    __syncthreads();
    int lane = tid & 63, wv = tid >> 6;
    for (int q = 0; q < 4; ++q) {
        int t = blockIdx.x * 16 + wv * 4 + q;
        double ar[7] = {0,0,0,0,0,0,0}, an[7] = {0,0,0,0,0,0,0};
        for (int j = 0; j < 16; ++j) {
            int d = j * 64 + lane;
            double xd = (double)x[t * 1024 + d];
#pragma unroll
            for (int e = 0; e < 7; ++e) {
                ar[e] += xd * (double)swr[d * 7 + e];
                an[e] += xd * (double)swn[d * 7 + e];
            }
        }
#pragma unroll
        for (int e = 0; e < 7; ++e) {
            for (int o = 32; o > 0; o >>= 1) {
                ar[e] += __shfl_xor(ar[e], o);
                an[e] += __shfl_xor(an[e], o);
            }
        }
        if (lane == 0) {
            double best = -1e300, second = -1e300; int b0 = 0, b1 = 0;
#pragma unroll
            for (int e = 0; e < 7; ++e) {
                double lg = ar[e] + (double)br[e];
                double z  = an[e] + (double)bn[e];
                double sp = (z > 30.0) ? (z + log1p(exp(-z))) : log1p(exp(z));
                double v  = lg + (double)noise[t * 7 + e] * sp;
                if (v > best)        { second = best; b1 = b0; best = v; b0 = e; }
                else if (v > second) { second = v; b1 = e; }
            }
            double ex = exp(second - best);
            idx0[t] = b0; idx1[t] = b1;
            p0[t] = (float)(1.0 / (1.0 + ex));
            p1[t] = (float)(ex / (1.0 + ex));
        }
    }
}

// ---------------- phase A: per-64-token-chunk per-expert counts + fp64 gate partials ----------------
__global__ void k_count(const int* __restrict__ idx0, const int* __restrict__ idx1,
                        const float* __restrict__ p0, const float* __restrict__ p1,
                        int* __restrict__ cntA, double* __restrict__ sumA) {
    int lane = threadIdx.x & 63;
    int chunk = (blockIdx.x * 256 + threadIdx.x) >> 6;
    int t = chunk * 64 + lane;
    int i0 = idx0[t], i1 = idx1[t];
    double q0 = (double)p0[t], q1 = (double)p1[t];
#pragma unroll
    for (int e = 0; e < 7; ++e) {
        unsigned long long m = __ballot((i0 == e) || (i1 == e));
        double q = (i0 == e ? q0 : 0.0) + (i1 == e ? q1 : 0.0);
        for (int o = 32; o > 0; o >>= 1) q += __shfl_xor(q, o);
        if (lane == 0) { cntA[e * 128 + chunk] = __popcll(m); sumA[e * 128 + chunk] = q; }
    }
}

// ---------------- phase B: exclusive scan of chunk counts + lbl -> out ----------------
__global__ void k_scanbase(const int* __restrict__ cntA, const double* __restrict__ sumA,
                           int* __restrict__ baseA, int* __restrict__ cnt,
                           float* __restrict__ out) {
    __shared__ int s[128];
    __shared__ double rd[128];
    __shared__ int rawc[7];
    __shared__ double ps[7];
    int tid = threadIdx.x;
    for (int e = 0; e < 7; ++e) {
        int v = 0;
        if (tid < 128) { v = cntA[e * 128 + tid]; s[tid] = v; }
        if (tid < 128) rd[tid] = sumA[e * 128 + tid];
        __syncthreads();
        for (int o = 1; o < 128; o <<= 1) {
            int add = 0;
            if (tid < 128 && tid >= o) add = s[tid - o];
            __syncthreads();
            if (tid < 128) s[tid] += add;
            __syncthreads();
        }
        if (tid < 128) baseA[e * 128 + tid] = s[tid] - v;
        if (tid == 127) { rawc[e] = s[127]; cnt[e] = (s[127] < CAPC) ? s[127] : CAPC; }
        for (int o = 64; o > 0; o >>= 1) {
            if (tid < o) rd[tid] += rd[tid + o];
            __syncthreads();
        }
        if (tid == 0) ps[e] = rd[0];
        __syncthreads();
    }
    if (tid == 0) {
        double acc = 0.0;
        for (int e = 0; e < 7; ++e) acc += ps[e] * (double)rawc[e];
        out[(long)NTOK * DDIM] = (float)(7.0 * acc / (8192.0 * 8192.0));
    }
}

// ---------------- phase C: slot assignment (FCFS, capacity-dropped) ----------------
__global__ void k_assign(const int* __restrict__ idx0, const int* __restrict__ idx1,
                         const int* __restrict__ baseA, int* __restrict__ slot_token,
                         int* __restrict__ ts0, int* __restrict__ ts1) {
    int lane = threadIdx.x & 63;
    int chunk = (blockIdx.x * 256 + threadIdx.x) >> 6;
    int t = chunk * 64 + lane;
    int i0 = idx0[t], i1 = idx1[t];
    int myts0 = -1, myts1 = -1;
    unsigned long long lt = (1ull << lane) - 1ull;
#pragma unroll
    for (int e = 0; e < 7; ++e) {
        bool has = (i0 == e) || (i1 == e);
        unsigned long long m = __ballot(has);
        int pre = __popcll(m & lt);
        int pos = baseA[e * 128 + chunk] + pre;
        if (has && pos < CAPC) {
            int slot = e * CPAD + pos;
            slot_token[slot] = t;
            if (i0 == e) myts0 = slot; else myts1 = slot;
        }
    }
    ts0[t] = myts0; ts1[t] = myts1;
}

// ---------------- fused MFMA GEMM: experts (blocks 0..1175) + shared (1176..1687) ----------------
// 128x128 tile, BK=64, global_load_lds width-16 staging (m97 pattern).
// LDS invariant: lane l lands at LDS base + l*16B => row (wv*4+i)*8+(l>>3), slot l&7,
// holding global chunk (l&7)^(l>>3); reader fetches chunk kg at slot kg^(row&7).
template <bool GATHER, bool MODE_H>
__global__ __launch_bounds__(256) void k_gemm(
    const u16* __restrict__ AbaseE, const u16* __restrict__ AbaseS,
    const int* __restrict__ gidx, const u16* __restrict__ zrow,
    const u16* __restrict__ WtE, const u16* __restrict__ WtS,
    const float* __restrict__ biasE, const float* __restrict__ biasS,
    u16* __restrict__ outE, u16* __restrict__ outS,
    const int* __restrict__ cnt) {
    __shared__ __align__(16) u16 ldsA[128 * 64];
    __shared__ __align__(16) u16 ldsB[128 * 64];
    int bid = blockIdx.x;
    int tid = threadIdx.x, lane = tid & 63, wv = tid >> 6;
    int lrow = lane >> 3, lkg = lane & 7;
    int kgs = lkg ^ lrow;

    int e = 0, my, nx;
    const u16* Ab; const u16* Bb; const float* bias; u16* outp; long ostride;
    bool gather = false;
    if (bid < EBLK) {
        e = bid / 168; int r = bid % 168; my = r >> 3; nx = r & 7;
        if (my * 128 >= cnt[e]) return;
        Ab = AbaseE + (GATHER ? 0L : (long)e * CPAD * 1024);
        Bb = WtE + ((long)e << 20);
        bias = biasE + e * 1024;
        outp = outE + (long)e * CPAD * 1024;
        gather = GATHER;
    } else {
        int sb = bid - EBLK; my = sb >> 3; nx = sb & 7;
        Ab = AbaseS; Bb = WtS; bias = biasS; outp = outS;
    }
    int m0 = my * 128, n0 = nx * 128;

    const u16* arow[4];
    const u16* brow[4];
#pragma unroll
    for (int i = 0; i < 4; ++i) {
        int r = (wv * 4 + i) * 8 + lrow;     // 0..127
        if (gather) {
            int tok = gidx[e * CPAD + m0 + r];
            arow[i] = (tok < NTOK) ? (AbaseE + (long)tok * DDIM) : zrow;
        } else {
            arow[i] = Ab + (long)(m0 + r) * DDIM;
        }
        brow[i] = Bb + (long)(n0 + r) * DDIM;
    }
    f32x4 acc[4][4];
#pragma unroll
    for (int a = 0; a < 4; ++a)
#pragma unroll
        for (int b = 0; b < 4; ++b) { f32x4 z = {0.f, 0.f, 0.f, 0.f}; acc[a][b] = z; }

    int wm = (wv >> 1) * 64, wn = (wv & 1) * 64;
    int rl = lane & 15, quad = lane >> 4;

    for (int k0 = 0; k0 < 1024; k0 += 64) {
#pragma unroll
        for (int i = 0; i < 4; ++i) {
            gl2lds16(arow[i] + k0 + kgs * 8, &ldsA[(wv * 4 + i) * 512]);
            gl2lds16(brow[i] + k0 + kgs * 8, &ldsB[(wv * 4 + i) * 512]);
        }
        __syncthreads();   // drains vmcnt -> staged tile visible
#pragma unroll
        for (int ks = 0; ks < 2; ++ks) {
            int kg = ks * 4 + quad;
            bf16x8 af[4], bf[4];
#pragma unroll
            for (int mi = 0; mi < 4; ++mi) {
                int row = wm + mi * 16 + rl;
                af[mi] = *(const bf16x8*)&ldsA[row * 64 + (kg ^ (row & 7)) * 8];
            }
#pragma unroll
            for (int ni = 0; ni < 4; ++ni) {
                int row = wn + ni * 16 + rl;
                bf[ni] = *(const bf16x8*)&ldsB[row * 64 + (kg ^ (row & 7)) * 8];
            }
#pragma unroll
            for (int mi = 0; mi < 4; ++mi)
#pragma unroll
                for (int ni = 0; ni < 4; ++ni)
                    acc[mi][ni] = __builtin_amdgcn_mfma_f32_16x16x32_bf16(
                        af[mi], bf[ni], acc[mi][ni], 0, 0, 0);
        }
        __syncthreads();   // all reads done before next tile overwrites
    }
    // epilogue: C/D layout col = lane&15, row = quad*4 + reg
#pragma unroll
    for (int ni = 0; ni < 4; ++ni) {
        int col = n0 + wn + ni * 16 + rl;
        float bv = bias[col];
#pragma unroll
        for (int mi = 0; mi < 4; ++mi) {
            int rowb = m0 + wm + mi * 16 + quad * 4;
#pragma unroll
            for (int r = 0; r < 4; ++r) {
                float v = acc[mi][ni][r] + bv;
                if constexpr (MODE_H) v = v > 0.f ? v : 0.f;
                outp[(long)(rowb + r) * DDIM + col] = f2bf(v);
            }
        }
    }
}

// ---------------- combine: out = Xs + g0*OutE[s0] + g1*OutE[s1] ----------------
__global__ __launch_bounds__(256) void k_combine(
    const u16* __restrict__ Xs, const u16* __restrict__ OutE,
    const int* __restrict__ ts0, const int* __restrict__ ts1,
    const float* __restrict__ p0, const float* __restrict__ p1,
    float* __restrict__ out) {
    int b = blockIdx.x;
    int d = threadIdx.x * 4;
    long base = (long)b * DDIM + d;
    ushort4 xs4 = *(const ushort4*)(Xs + base);
    float r0 = bf2f(xs4.x), r1 = bf2f(xs4.y), r2 = bf2f(xs4.z), r3 = bf2f(xs4.w);
    int s0 = ts0[b], s1 = ts1[b];
    if (s0 >= 0) {
        float g = p0[b];
        ushort4 o4 = *(const ushort4*)(OutE + (long)s0 * DDIM + d);
        r0 += g * bf2f(o4.x); r1 += g * bf2f(o4.y); r2 += g * bf2f(o4.z); r3 += g * bf2f(o4.w);
    }
    if (s1 >= 0) {
        float g = p1[b];
        ushort4 o4 = *(const ushort4*)(OutE + (long)s1 * DDIM + d);
        r0 += g * bf2f(o4.x); r1 += g * bf2f(o4.y); r2 += g * bf2f(o4.z); r3 += g * bf2f(o4.w);
    }
    float4 w; w.x = r0; w.y = r1; w.z = r2; w.w = r3;
    *(float4*)(out + base) = w;
}

extern "C" void kernel_launch(void* const* d_in, const int* in_sizes, int n_in,
                              void* d_out, int out_size, void* d_ws, size_t ws_size,
                              hipStream_t stream) {
    const float* x    = (const float*)d_in[0];
    const float* noise= (const float*)d_in[1];
    const float* Wr   = (const float*)d_in[2];
    const float* br   = (const float*)d_in[3];
    const float* Wn   = (const float*)d_in[4];
    const float* bn   = (const float*)d_in[5];
    const float* W1   = (const float*)d_in[6];
    const float* b1   = (const float*)d_in[7];
    const float* W2   = (const float*)d_in[8];
    const float* b2   = (const float*)d_in[9];
    const float* Ws1  = (const float*)d_in[10];
    const float* bs1  = (const float*)d_in[11];
    const float* Ws2  = (const float*)d_in[12];
    const float* bs2  = (const float*)d_in[13];
    float* out = (float*)d_out;
    char* ws = (char*)d_ws;

    // Arena ~145 MB. Wt/Wst reused in two phases (W1/Ws1, then W2/Ws2).
    size_t off = 0;
    auto alloc = [&](size_t bytes) { size_t o = off; off += (bytes + 255) & ~(size_t)255; return o; };
    u16*  Wt   = (u16*)(ws + alloc(7ull * 1048576 * 2));
    u16*  Wst  = (u16*)(ws + alloc(1048576ull * 2));
    u16*  xb   = (u16*)(ws + alloc((size_t)NTOK * 1024 * 2));
    u16*  He   = (u16*)(ws + alloc((size_t)NEXP * CPAD * 1024 * 2));
    u16*  Hs   = (u16*)(ws + alloc((size_t)NTOK * 1024 * 2));
    u16*  OutE = (u16*)(ws + alloc((size_t)NEXP * CPAD * 1024 * 2));
    u16*  Xs   = (u16*)(ws + alloc((size_t)NTOK * 1024 * 2));
    int*  idx0 = (int*)(ws + alloc(NTOK * 4));
    int*  idx1 = (int*)(ws + alloc(NTOK * 4));
    float* p0  = (float*)(ws + alloc(NTOK * 4));
    float* p1  = (float*)(ws + alloc(NTOK * 4));
    int*  ts0  = (int*)(ws + alloc(NTOK * 4));
    int*  ts1  = (int*)(ws + alloc(NTOK * 4));
    int*  slot_token = (int*)(ws + alloc(NEXP * CPAD * 4));
    int*  cntA = (int*)(ws + alloc(7 * 128 * 4));
    int*  baseA= (int*)(ws + alloc(7 * 128 * 4));
    double* sumA = (double*)(ws + alloc(7 * 128 * 8));
    int*  cnt    = (int*)(ws + alloc(8 * 4));
    u16*  zrow   = (u16*)(ws + alloc(1024 * 2));

    if (off > ws_size) {
        k_zero<<<2048, 256, 0, stream>>>(out, (long)out_size);
        return;
    }

    k_prep<<<4096, 256, 0, stream>>>(x, xb, slot_token, zrow);
    k_transpose<<<dim3(4, 128, 8), 256, 0, stream>>>(W1, Ws1, Wt, Wst);   // phase 1
    k_router<<<512, 256, 0, stream>>>(x, noise, Wr, br, Wn, bn, idx0, idx1, p0, p1);
    k_count<<<32, 256, 0, stream>>>(idx0, idx1, p0, p1, cntA, sumA);
    k_scanbase<<<1, 256, 0, stream>>>(cntA, sumA, baseA, cnt, out);
    k_assign<<<32, 256, 0, stream>>>(idx0, idx1, baseA, slot_token, ts0, ts1);

    // fused layer 1: experts (gather xb via slot_token) + shared, relu -> bf16 He/Hs
    k_gemm<true, true><<<TBLK, 256, 0, stream>>>(
        xb, xb, slot_token, zrow, Wt, Wst, b1, bs1, He, Hs, cnt);

    k_transpose<<<dim3(4, 128, 8), 256, 0, stream>>>(W2, Ws2, Wt, Wst);   // phase 2

    // fused layer 2: -> bf16 OutE/Xs (+b2/bs2)
    k_gemm<false, false><<<TBLK, 256, 0, stream>>>(
        He, Hs, nullptr, zrow, Wt, Wst, b2, bs2, OutE, Xs, cnt);

    k_combine<<<NTOK, 256, 0, stream>>>(Xs, OutE, ts0, ts1, p0, p1, out);
    (void)in_sizes; (void)n_in; (void)out_size;
}

// Round 6
// 424.478 us; speedup vs baseline: 1.1471x; 1.1471x over previous
//
#include <hip/hip_runtime.h>
#include <math.h>

typedef unsigned short u16;
typedef __attribute__((ext_vector_type(4))) float f32x4;
typedef __bf16 bf16x8 __attribute__((ext_vector_type(8)));

#define NTOK 8192
#define DDIM 1024
#define NEXP 7
#define CAPC 2574      /* int(8192*2/7*1.1) */
#define CPAD 2688      /* 21*128 */
#define EBLK 1176      /* 7 experts * 21 mblk * 8 nblk */
#define TBLK 1688      /* + 64*8 shared blocks */

__device__ inline float bf2f(u16 u) {
    union { unsigned int i; float f; } c; c.i = ((unsigned int)u) << 16; return c.f;
}
__device__ inline u16 f2bf(float f) {
    union { float f; unsigned int i; } c; c.f = f;
    unsigned int u = c.i;
    unsigned int r = (u + 0x7fffu + ((u >> 16) & 1u)) >> 16;
    return (u16)r;
}

__device__ inline void gl2lds16(const u16* g, const u16* l) {
    __builtin_amdgcn_global_load_lds(
        (const __attribute__((address_space(1))) unsigned int*)g,
        (__attribute__((address_space(3))) unsigned int*)l, 16, 0, 0);
}

// ---------------- guard: zero the output (ws_size-too-small diagnostic) ----------------
__global__ void k_zero(float* out, long n) {
    long i = (long)blockIdx.x * 256 + threadIdx.x;
    long stride = (long)gridDim.x * 256;
    for (; i < n; i += stride) out[i] = 0.f;
}

// ---------------- fused prep: blocks 0..4095 = x->bf16 conv + init; 4096..8191 = transpose W1/Ws1 ----------------
__global__ void k_prep(const float* __restrict__ x, u16* __restrict__ xb,
                       int* __restrict__ slot_token, u16* __restrict__ zrow,
                       const float* __restrict__ srcE, const float* __restrict__ srcS,
                       u16* __restrict__ Wt, u16* __restrict__ Wst) {
    int bid = blockIdx.x, tid = threadIdx.x;
    if (bid < 4096) {
        int gid = bid * 256 + tid;
        int i = gid * 8;
        float4 a = *(const float4*)(x + i);
        float4 b = *(const float4*)(x + i + 4);
        ushort4 o0; o0.x = f2bf(a.x); o0.y = f2bf(a.y); o0.z = f2bf(a.z); o0.w = f2bf(a.w);
        ushort4 o1; o1.x = f2bf(b.x); o1.y = f2bf(b.y); o1.z = f2bf(b.z); o1.w = f2bf(b.w);
        *(ushort4*)(xb + i) = o0;
        *(ushort4*)(xb + i + 4) = o1;
        if (gid < DDIM) zrow[gid] = 0;
        if (gid < NEXP * CPAD) slot_token[gid] = NTOK;
    } else {
        int tb = bid - 4096;
        int z = tb >> 9; int rem = tb & 511;
        int y = rem >> 2; int xq = rem & 3;
        const float* src; u16* dst;
        if (z < 7) { src = srcE + (long)z * 1048576; dst = Wt + (long)z * 1048576; }
        else       { src = srcS;                     dst = Wst; }
        int n = xq * 256 + tid;
        int k0 = y * 8;
        u16 v[8];
#pragma unroll
        for (int j = 0; j < 8; ++j) v[j] = f2bf(src[(long)(k0 + j) * 1024 + n]);
        ushort4 a; a.x = v[0]; a.y = v[1]; a.z = v[2]; a.w = v[3];
        ushort4 b; b.x = v[4]; b.y = v[5]; b.z = v[6]; b.w = v[7];
        *(ushort4*)(dst + (long)n * 1024 + k0) = a;
        *(ushort4*)(dst + (long)n * 1024 + k0 + 4) = b;
    }
}

// ---------------- weight transpose phase 2: fp32 [K][N] -> bf16 [N][K] ----------------
__global__ void k_transpose(const float* __restrict__ srcE, const float* __restrict__ srcS,
                            u16* __restrict__ Wt, u16* __restrict__ Wst) {
    int z = blockIdx.z;
    const float* src; u16* dst;
    if (z < 7) { src = srcE + (long)z * 1048576; dst = Wt + (long)z * 1048576; }
    else       { src = srcS;                     dst = Wst; }
    int n = blockIdx.x * 256 + threadIdx.x;
    int k0 = blockIdx.y * 8;
    u16 v[8];
#pragma unroll
    for (int j = 0; j < 8; ++j) v[j] = f2bf(src[(long)(k0 + j) * 1024 + n]);
    ushort4 a; a.x = v[0]; a.y = v[1]; a.z = v[2]; a.w = v[3];
    ushort4 b; b.x = v[4]; b.y = v[5]; b.z = v[6]; b.w = v[7];
    *(ushort4*)(dst + (long)n * 1024 + k0) = a;
    *(ushort4*)(dst + (long)n * 1024 + k0 + 4) = b;
}

// ---------------- router: fp64 logits, softplus-noise, top-2, softmax ----------------
// round-4 measured-good config: 2048 blocks x 4 waves, 1 token per wave
__global__ __launch_bounds__(256) void k_router(
    const float* __restrict__ x, const float* __restrict__ noise,
    const float* __restrict__ Wr, const float* __restrict__ br,
    const float* __restrict__ Wn, const float* __restrict__ bn,
    int* __restrict__ idx0, int* __restrict__ idx1,
    float* __restrict__ p0, float* __restrict__ p1) {
    __shared__ float swr[7168];
    __shared__ float swn[7168];
    int tid = threadIdx.x;
    for (int i = tid; i < 7168; i += 256) { swr[i] = Wr[i]; swn[i] = Wn[i]; }
    __syncthreads();
    int lane = tid & 63, wv = tid >> 6;
    int t = blockIdx.x * 4 + wv;
    double ar[7] = {0,0,0,0,0,0,0}, an[7] = {0,0,0,0,0,0,0};
    for (int j = 0; j < 16; ++j) {
        int d = j * 64 + lane;
        double xd = (double)x[t * 1024 + d];
#pragma unroll
        for (int e = 0; e < 7; ++e) {
            ar[e] += xd * (double)swr[d * 7 + e];
            an[e] += xd * (double)swn[d * 7 + e];
        }
    }
#pragma unroll
    for (int e = 0; e < 7; ++e) {
        for (int o = 32; o > 0; o >>= 1) {
            ar[e] += __shfl_xor(ar[e], o);
            an[e] += __shfl_xor(an[e], o);
        }
    }
    if (lane == 0) {
        double best = -1e300, second = -1e300; int b0 = 0, b1 = 0;
#pragma unroll
        for (int e = 0; e < 7; ++e) {
            double lg = ar[e] + (double)br[e];
            double z  = an[e] + (double)bn[e];
            double sp = (z > 30.0) ? (z + log1p(exp(-z))) : log1p(exp(z));
            double v  = lg + (double)noise[t * 7 + e] * sp;
            if (v > best)        { second = best; b1 = b0; best = v; b0 = e; }
            else if (v > second) { second = v; b1 = e; }
        }
        double ex = exp(second - best);
        idx0[t] = b0; idx1[t] = b1;
        p0[t] = (float)(1.0 / (1.0 + ex));
        p1[t] = (float)(ex / (1.0 + ex));
    }
}

// ---------------- phase A: per-64-token-chunk per-expert counts + fp64 gate partials ----------------
__global__ void k_count(const int* __restrict__ idx0, const int* __restrict__ idx1,
                        const float* __restrict__ p0, const float* __restrict__ p1,
                        int* __restrict__ cntA, double* __restrict__ sumA) {
    int lane = threadIdx.x & 63;
    int chunk = (blockIdx.x * 256 + threadIdx.x) >> 6;
    int t = chunk * 64 + lane;
    int i0 = idx0[t], i1 = idx1[t];
    double q0 = (double)p0[t], q1 = (double)p1[t];
#pragma unroll
    for (int e = 0; e < 7; ++e) {
        unsigned long long m = __ballot((i0 == e) || (i1 == e));
        double q = (i0 == e ? q0 : 0.0) + (i1 == e ? q1 : 0.0);
        for (int o = 32; o > 0; o >>= 1) q += __shfl_xor(q, o);
        if (lane == 0) { cntA[e * 128 + chunk] = __popcll(m); sumA[e * 128 + chunk] = q; }
    }
}

// ---------------- phase B: exclusive scan of chunk counts + lbl -> out ----------------
__global__ void k_scanbase(const int* __restrict__ cntA, const double* __restrict__ sumA,
                           int* __restrict__ baseA, int* __restrict__ cnt,
                           float* __restrict__ out) {
    __shared__ int s[128];
    __shared__ double rd[128];
    __shared__ int rawc[7];
    __shared__ double ps[7];
    int tid = threadIdx.x;
    for (int e = 0; e < 7; ++e) {
        int v = 0;
        if (tid < 128) { v = cntA[e * 128 + tid]; s[tid] = v; }
        if (tid < 128) rd[tid] = sumA[e * 128 + tid];
        __syncthreads();
        for (int o = 1; o < 128; o <<= 1) {
            int add = 0;
            if (tid < 128 && tid >= o) add = s[tid - o];
            __syncthreads();
            if (tid < 128) s[tid] += add;
            __syncthreads();
        }
        if (tid < 128) baseA[e * 128 + tid] = s[tid] - v;
        if (tid == 127) { rawc[e] = s[127]; cnt[e] = (s[127] < CAPC) ? s[127] : CAPC; }
        for (int o = 64; o > 0; o >>= 1) {
            if (tid < o) rd[tid] += rd[tid + o];
            __syncthreads();
        }
        if (tid == 0) ps[e] = rd[0];
        __syncthreads();
    }
    if (tid == 0) {
        double acc = 0.0;
        for (int e = 0; e < 7; ++e) acc += ps[e] * (double)rawc[e];
        out[(long)NTOK * DDIM] = (float)(7.0 * acc / (8192.0 * 8192.0));
    }
}

// ---------------- phase C: slot assignment (FCFS, capacity-dropped) ----------------
__global__ void k_assign(const int* __restrict__ idx0, const int* __restrict__ idx1,
                         const int* __restrict__ baseA, int* __restrict__ slot_token,
                         int* __restrict__ ts0, int* __restrict__ ts1) {
    int lane = threadIdx.x & 63;
    int chunk = (blockIdx.x * 256 + threadIdx.x) >> 6;
    int t = chunk * 64 + lane;
    int i0 = idx0[t], i1 = idx1[t];
    int myts0 = -1, myts1 = -1;
    unsigned long long lt = (1ull << lane) - 1ull;
#pragma unroll
    for (int e = 0; e < 7; ++e) {
        bool has = (i0 == e) || (i1 == e);
        unsigned long long m = __ballot(has);
        int pre = __popcll(m & lt);
        int pos = baseA[e * 128 + chunk] + pre;
        if (has && pos < CAPC) {
            int slot = e * CPAD + pos;
            slot_token[slot] = t;
            if (i0 == e) myts0 = slot; else myts1 = slot;
        }
    }
    ts0[t] = myts0; ts1[t] = myts1;
}

// ---------------- fused MFMA GEMM: experts (blocks 0..1175) + shared (1176..1687) ----------------
// 128x128 tile, BK=64, global_load_lds width-16 staging (m97 pattern).
template <bool GATHER, bool MODE_H>
__global__ __launch_bounds__(256) void k_gemm(
    const u16* __restrict__ AbaseE, const u16* __restrict__ AbaseS,
    const int* __restrict__ gidx, const u16* __restrict__ zrow,
    const u16* __restrict__ WtE, const u16* __restrict__ WtS,
    const float* __restrict__ biasE, const float* __restrict__ biasS,
    u16* __restrict__ outE, u16* __restrict__ outS,
    const int* __restrict__ cnt) {
    __shared__ __align__(16) u16 ldsA[128 * 64];
    __shared__ __align__(16) u16 ldsB[128 * 64];
    int bid = blockIdx.x;
    int tid = threadIdx.x, lane = tid & 63, wv = tid >> 6;
    int lrow = lane >> 3, lkg = lane & 7;
    int kgs = lkg ^ lrow;

    int e = 0, my, nx;
    const u16* Ab; const u16* Bb; const float* bias; u16* outp;
    bool gather = false;
    if (bid < EBLK) {
        e = bid / 168; int r = bid % 168; my = r >> 3; nx = r & 7;
        if (my * 128 >= cnt[e]) return;
        Ab = AbaseE + (GATHER ? 0L : (long)e * CPAD * 1024);
        Bb = WtE + ((long)e << 20);
        bias = biasE + e * 1024;
        outp = outE + (long)e * CPAD * 1024;
        gather = GATHER;
    } else {
        int sb = bid - EBLK; my = sb >> 3; nx = sb & 7;
        Ab = AbaseS; Bb = WtS; bias = biasS; outp = outS;
    }
    int m0 = my * 128, n0 = nx * 128;

    const u16* arow[4];
    const u16* brow[4];
#pragma unroll
    for (int i = 0; i < 4; ++i) {
        int r = (wv * 4 + i) * 8 + lrow;     // 0..127
        if (gather) {
            int tok = gidx[e * CPAD + m0 + r];
            arow[i] = (tok < NTOK) ? (AbaseE + (long)tok * DDIM) : zrow;
        } else {
            arow[i] = Ab + (long)(m0 + r) * DDIM;
        }
        brow[i] = Bb + (long)(n0 + r) * DDIM;
    }
    f32x4 acc[4][4];
#pragma unroll
    for (int a = 0; a < 4; ++a)
#pragma unroll
        for (int b = 0; b < 4; ++b) { f32x4 z = {0.f, 0.f, 0.f, 0.f}; acc[a][b] = z; }

    int wm = (wv >> 1) * 64, wn = (wv & 1) * 64;
    int rl = lane & 15, quad = lane >> 4;

    for (int k0 = 0; k0 < 1024; k0 += 64) {
#pragma unroll
        for (int i = 0; i < 4; ++i) {
            gl2lds16(arow[i] + k0 + kgs * 8, &ldsA[(wv * 4 + i) * 512]);
            gl2lds16(brow[i] + k0 + kgs * 8, &ldsB[(wv * 4 + i) * 512]);
        }
        __syncthreads();   // drains vmcnt -> staged tile visible
#pragma unroll
        for (int ks = 0; ks < 2; ++ks) {
            int kg = ks * 4 + quad;
            bf16x8 af[4], bf[4];
#pragma unroll
            for (int mi = 0; mi < 4; ++mi) {
                int row = wm + mi * 16 + rl;
                af[mi] = *(const bf16x8*)&ldsA[row * 64 + (kg ^ (row & 7)) * 8];
            }
#pragma unroll
            for (int ni = 0; ni < 4; ++ni) {
                int row = wn + ni * 16 + rl;
                bf[ni] = *(const bf16x8*)&ldsB[row * 64 + (kg ^ (row & 7)) * 8];
            }
#pragma unroll
            for (int mi = 0; mi < 4; ++mi)
#pragma unroll
                for (int ni = 0; ni < 4; ++ni)
                    acc[mi][ni] = __builtin_amdgcn_mfma_f32_16x16x32_bf16(
                        af[mi], bf[ni], acc[mi][ni], 0, 0, 0);
        }
        __syncthreads();   // all reads done before next tile overwrites
    }
    // epilogue: C/D layout col = lane&15, row = quad*4 + reg
#pragma unroll
    for (int ni = 0; ni < 4; ++ni) {
        int col = n0 + wn + ni * 16 + rl;
        float bv = bias[col];
#pragma unroll
        for (int mi = 0; mi < 4; ++mi) {
            int rowb = m0 + wm + mi * 16 + quad * 4;
#pragma unroll
            for (int r = 0; r < 4; ++r) {
                float v = acc[mi][ni][r] + bv;
                if constexpr (MODE_H) v = v > 0.f ? v : 0.f;
                outp[(long)(rowb + r) * DDIM + col] = f2bf(v);
            }
        }
    }
}

// ---------------- combine: out = Xs + g0*OutE[s0] + g1*OutE[s1] ----------------
__global__ __launch_bounds__(256) void k_combine(
    const u16* __restrict__ Xs, const u16* __restrict__ OutE,
    const int* __restrict__ ts0, const int* __restrict__ ts1,
    const float* __restrict__ p0, const float* __restrict__ p1,
    float* __restrict__ out) {
    int b = blockIdx.x;
    int d = threadIdx.x * 4;
    long base = (long)b * DDIM + d;
    ushort4 xs4 = *(const ushort4*)(Xs + base);
    float r0 = bf2f(xs4.x), r1 = bf2f(xs4.y), r2 = bf2f(xs4.z), r3 = bf2f(xs4.w);
    int s0 = ts0[b], s1 = ts1[b];
    if (s0 >= 0) {
        float g = p0[b];
        ushort4 o4 = *(const ushort4*)(OutE + (long)s0 * DDIM + d);
        r0 += g * bf2f(o4.x); r1 += g * bf2f(o4.y); r2 += g * bf2f(o4.z); r3 += g * bf2f(o4.w);
    }
    if (s1 >= 0) {
        float g = p1[b];
        ushort4 o4 = *(const ushort4*)(OutE + (long)s1 * DDIM + d);
        r0 += g * bf2f(o4.x); r1 += g * bf2f(o4.y); r2 += g * bf2f(o4.z); r3 += g * bf2f(o4.w);
    }
    float4 w; w.x = r0; w.y = r1; w.z = r2; w.w = r3;
    *(float4*)(out + base) = w;
}

extern "C" void kernel_launch(void* const* d_in, const int* in_sizes, int n_in,
                              void* d_out, int out_size, void* d_ws, size_t ws_size,
                              hipStream_t stream) {
    const float* x    = (const float*)d_in[0];
    const float* noise= (const float*)d_in[1];
    const float* Wr   = (const float*)d_in[2];
    const float* br   = (const float*)d_in[3];
    const float* Wn   = (const float*)d_in[4];
    const float* bn   = (const float*)d_in[5];
    const float* W1   = (const float*)d_in[6];
    const float* b1   = (const float*)d_in[7];
    const float* W2   = (const float*)d_in[8];
    const float* b2   = (const float*)d_in[9];
    const float* Ws1  = (const float*)d_in[10];
    const float* bs1  = (const float*)d_in[11];
    const float* Ws2  = (const float*)d_in[12];
    const float* bs2  = (const float*)d_in[13];
    float* out = (float*)d_out;
    char* ws = (char*)d_ws;

    // Arena ~145 MB. Wt/Wst reused in two phases (W1/Ws1, then W2/Ws2).
    size_t off = 0;
    auto alloc = [&](size_t bytes) { size_t o = off; off += (bytes + 255) & ~(size_t)255; return o; };
    u16*  Wt   = (u16*)(ws + alloc(7ull * 1048576 * 2));
    u16*  Wst  = (u16*)(ws + alloc(1048576ull * 2));
    u16*  xb   = (u16*)(ws + alloc((size_t)NTOK * 1024 * 2));
    u16*  He   = (u16*)(ws + alloc((size_t)NEXP * CPAD * 1024 * 2));
    u16*  Hs   = (u16*)(ws + alloc((size_t)NTOK * 1024 * 2));
    u16*  OutE = (u16*)(ws + alloc((size_t)NEXP * CPAD * 1024 * 2));
    u16*  Xs   = (u16*)(ws + alloc((size_t)NTOK * 1024 * 2));
    int*  idx0 = (int*)(ws + alloc(NTOK * 4));
    int*  idx1 = (int*)(ws + alloc(NTOK * 4));
    float* p0  = (float*)(ws + alloc(NTOK * 4));
    float* p1  = (float*)(ws + alloc(NTOK * 4));
    int*  ts0  = (int*)(ws + alloc(NTOK * 4));
    int*  ts1  = (int*)(ws + alloc(NTOK * 4));
    int*  slot_token = (int*)(ws + alloc(NEXP * CPAD * 4));
    int*  cntA = (int*)(ws + alloc(7 * 128 * 4));
    int*  baseA= (int*)(ws + alloc(7 * 128 * 4));
    double* sumA = (double*)(ws + alloc(7 * 128 * 8));
    int*  cnt    = (int*)(ws + alloc(8 * 4));
    u16*  zrow   = (u16*)(ws + alloc(1024 * 2));

    if (off > ws_size) {
        k_zero<<<2048, 256, 0, stream>>>(out, (long)out_size);
        return;
    }

    // fused: x->bf16 + inits + transpose phase 1 (W1/Ws1)
    k_prep<<<8192, 256, 0, stream>>>(x, xb, slot_token, zrow, W1, Ws1, Wt, Wst);
    k_router<<<2048, 256, 0, stream>>>(x, noise, Wr, br, Wn, bn, idx0, idx1, p0, p1);
    k_count<<<32, 256, 0, stream>>>(idx0, idx1, p0, p1, cntA, sumA);
    k_scanbase<<<1, 256, 0, stream>>>(cntA, sumA, baseA, cnt, out);
    k_assign<<<32, 256, 0, stream>>>(idx0, idx1, baseA, slot_token, ts0, ts1);

    // fused layer 1: experts (gather xb via slot_token) + shared, relu -> bf16 He/Hs
    k_gemm<true, true><<<TBLK, 256, 0, stream>>>(
        xb, xb, slot_token, zrow, Wt, Wst, b1, bs1, He, Hs, cnt);

    k_transpose<<<dim3(4, 128, 8), 256, 0, stream>>>(W2, Ws2, Wt, Wst);   // phase 2

    // fused layer 2: -> bf16 OutE/Xs (+b2/bs2)
    k_gemm<false, false><<<TBLK, 256, 0, stream>>>(
        He, Hs, nullptr, zrow, Wt, Wst, b2, bs2, OutE, Xs, cnt);

    k_combine<<<NTOK, 256, 0, stream>>>(Xs, OutE, ts0, ts1, p0, p1, out);
    (void)in_sizes; (void)n_in; (void)out_size;
}

// Round 7
// 402.156 us; speedup vs baseline: 1.2108x; 1.0555x over previous
//
#include <hip/hip_runtime.h>
#include <math.h>

typedef unsigned short u16;
typedef __attribute__((ext_vector_type(4))) float f32x4;
typedef __bf16 bf16x8 __attribute__((ext_vector_type(8)));

#define NTOK 8192
#define DDIM 1024
#define NEXP 7
#define CAPC 2574      /* int(8192*2/7*1.1) */
#define CPAD 2688      /* 21*128 */
#define EBLK 1176      /* 7 experts * 21 mblk * 8 nblk */
#define TBLK 1688      /* + 64*8 shared blocks */

__device__ inline float bf2f(u16 u) {
    union { unsigned int i; float f; } c; c.i = ((unsigned int)u) << 16; return c.f;
}
__device__ inline u16 f2bf(float f) {
    union { float f; unsigned int i; } c; c.f = f;
    unsigned int u = c.i;
    unsigned int r = (u + 0x7fffu + ((u >> 16) & 1u)) >> 16;
    return (u16)r;
}

__device__ inline void gl2lds16(const u16* g, const u16* l) {
    __builtin_amdgcn_global_load_lds(
        (const __attribute__((address_space(1))) unsigned int*)g,
        (__attribute__((address_space(3))) unsigned int*)l, 16, 0, 0);
}

// ---------------- guard: zero the output (ws_size-too-small diagnostic) ----------------
__global__ void k_zero(float* out, long n) {
    long i = (long)blockIdx.x * 256 + threadIdx.x;
    long stride = (long)gridDim.x * 256;
    for (; i < n; i += stride) out[i] = 0.f;
}

// ---------------- fused prep ----------------
// blocks 0..4095: x->bf16 + inits; 4096..8191: transpose W1/Ws1 -> Wt/Wst;
// 8192..12287 (only when sep): transpose W2/Ws2 -> Wt2/Wst2.
__global__ void k_prep(const float* __restrict__ x, u16* __restrict__ xb,
                       int* __restrict__ slot_token, u16* __restrict__ zrow,
                       const float* __restrict__ W1, const float* __restrict__ Ws1,
                       u16* __restrict__ Wt, u16* __restrict__ Wst,
                       const float* __restrict__ W2, const float* __restrict__ Ws2,
                       u16* __restrict__ Wt2, u16* __restrict__ Wst2) {
    int bid = blockIdx.x, tid = threadIdx.x;
    if (bid < 4096) {
        int gid = bid * 256 + tid;
        int i = gid * 8;
        float4 a = *(const float4*)(x + i);
        float4 b = *(const float4*)(x + i + 4);
        ushort4 o0; o0.x = f2bf(a.x); o0.y = f2bf(a.y); o0.z = f2bf(a.z); o0.w = f2bf(a.w);
        ushort4 o1; o1.x = f2bf(b.x); o1.y = f2bf(b.y); o1.z = f2bf(b.z); o1.w = f2bf(b.w);
        *(ushort4*)(xb + i) = o0;
        *(ushort4*)(xb + i + 4) = o1;
        if (gid < DDIM) zrow[gid] = 0;
        if (gid < NEXP * CPAD) slot_token[gid] = NTOK;
        return;
    }
    int phase2 = (bid >= 8192);
    int tb = bid - (phase2 ? 8192 : 4096);
    const float* srcE = phase2 ? W2 : W1;
    const float* srcS = phase2 ? Ws2 : Ws1;
    u16* dE = phase2 ? Wt2 : Wt;
    u16* dS = phase2 ? Wst2 : Wst;
    int z = tb >> 9; int rem = tb & 511;
    int y = rem >> 2; int xq = rem & 3;
    const float* src; u16* dst;
    if (z < 7) { src = srcE + (long)z * 1048576; dst = dE + (long)z * 1048576; }
    else       { src = srcS;                     dst = dS; }
    int n = xq * 256 + tid;
    int k0 = y * 8;
    u16 v[8];
#pragma unroll
    for (int j = 0; j < 8; ++j) v[j] = f2bf(src[(long)(k0 + j) * 1024 + n]);
    ushort4 a; a.x = v[0]; a.y = v[1]; a.z = v[2]; a.w = v[3];
    ushort4 b; b.x = v[4]; b.y = v[5]; b.z = v[6]; b.w = v[7];
    *(ushort4*)(dst + (long)n * 1024 + k0) = a;
    *(ushort4*)(dst + (long)n * 1024 + k0 + 4) = b;
}

// ---------------- weight transpose phase 2 (fallback when !sep) ----------------
__global__ void k_transpose(const float* __restrict__ srcE, const float* __restrict__ srcS,
                            u16* __restrict__ Wt, u16* __restrict__ Wst) {
    int z = blockIdx.z;
    const float* src; u16* dst;
    if (z < 7) { src = srcE + (long)z * 1048576; dst = Wt + (long)z * 1048576; }
    else       { src = srcS;                     dst = Wst; }
    int n = blockIdx.x * 256 + threadIdx.x;
    int k0 = blockIdx.y * 8;
    u16 v[8];
#pragma unroll
    for (int j = 0; j < 8; ++j) v[j] = f2bf(src[(long)(k0 + j) * 1024 + n]);
    ushort4 a; a.x = v[0]; a.y = v[1]; a.z = v[2]; a.w = v[3];
    ushort4 b; b.x = v[4]; b.y = v[5]; b.z = v[6]; b.w = v[7];
    *(ushort4*)(dst + (long)n * 1024 + k0) = a;
    *(ushort4*)(dst + (long)n * 1024 + k0 + 4) = b;
}

// ---------------- router main: fp64 dot-products only (no libm -> low VGPR) ----------------
// 1024 blocks x 512 thr; 1 token per wave
__global__ __launch_bounds__(512) void k_router(
    const float* __restrict__ x,
    const float* __restrict__ Wr, const float* __restrict__ Wn,
    double* __restrict__ arO, double* __restrict__ anO) {
    __shared__ float swr[7168];
    __shared__ float swn[7168];
    int tid = threadIdx.x;
    for (int i = tid; i < 7168; i += 512) { swr[i] = Wr[i]; swn[i] = Wn[i]; }
    __syncthreads();
    int lane = tid & 63, wv = tid >> 6;
    int t = blockIdx.x * 8 + wv;
    double ar[7] = {0,0,0,0,0,0,0}, an[7] = {0,0,0,0,0,0,0};
    for (int j = 0; j < 16; ++j) {
        int d = j * 64 + lane;
        double xd = (double)x[t * 1024 + d];
#pragma unroll
        for (int e = 0; e < 7; ++e) {
            ar[e] += xd * (double)swr[d * 7 + e];
            an[e] += xd * (double)swn[d * 7 + e];
        }
    }
#pragma unroll
    for (int e = 0; e < 7; ++e) {
        for (int o = 32; o > 0; o >>= 1) {
            ar[e] += __shfl_xor(ar[e], o);
            an[e] += __shfl_xor(an[e], o);
        }
    }
    if (lane == 0) {
#pragma unroll
        for (int e = 0; e < 7; ++e) { arO[t * 7 + e] = ar[e]; anO[t * 7 + e] = an[e]; }
    }
}

// ---------------- router tail + count: softplus/top-2/softmax, then chunk ballots ----------------
// 32 blocks x 256 thr; thread t = token t; wave = one 64-token chunk
__global__ void k_tail(const double* __restrict__ arO, const double* __restrict__ anO,
                       const float* __restrict__ noise,
                       const float* __restrict__ br, const float* __restrict__ bn,
                       int* __restrict__ idx0, int* __restrict__ idx1,
                       float* __restrict__ p0, float* __restrict__ p1,
                       int* __restrict__ cntA, double* __restrict__ sumA) {
    int t = blockIdx.x * 256 + threadIdx.x;
    int lane = threadIdx.x & 63;
    double best = -1e300, second = -1e300; int b0 = 0, b1 = 0;
#pragma unroll
    for (int e = 0; e < 7; ++e) {
        double lg = arO[t * 7 + e] + (double)br[e];
        double z  = anO[t * 7 + e] + (double)bn[e];
        double sp = (z > 30.0) ? (z + log1p(exp(-z))) : log1p(exp(z));
        double v  = lg + (double)noise[t * 7 + e] * sp;
        if (v > best)        { second = best; b1 = b0; best = v; b0 = e; }
        else if (v > second) { second = v; b1 = e; }
    }
    double ex = exp(second - best);
    float q0 = (float)(1.0 / (1.0 + ex));
    float q1 = (float)(ex / (1.0 + ex));
    idx0[t] = b0; idx1[t] = b1; p0[t] = q0; p1[t] = q1;
    // fused count: chunk = t>>6, uniform within wave
    int chunk = t >> 6;
    double dq0 = (double)q0, dq1 = (double)q1;
#pragma unroll
    for (int e = 0; e < 7; ++e) {
        unsigned long long m = __ballot((b0 == e) || (b1 == e));
        double q = (b0 == e ? dq0 : 0.0) + (b1 == e ? dq1 : 0.0);
        for (int o = 32; o > 0; o >>= 1) q += __shfl_xor(q, o);
        if (lane == 0) { cntA[e * 128 + chunk] = __popcll(m); sumA[e * 128 + chunk] = q; }
    }
}

// ---------------- phase B: exclusive scan of chunk counts + lbl -> out ----------------
__global__ void k_scanbase(const int* __restrict__ cntA, const double* __restrict__ sumA,
                           int* __restrict__ baseA, int* __restrict__ cnt,
                           float* __restrict__ out) {
    __shared__ int s[128];
    __shared__ double rd[128];
    __shared__ int rawc[7];
    __shared__ double ps[7];
    int tid = threadIdx.x;
    for (int e = 0; e < 7; ++e) {
        int v = 0;
        if (tid < 128) { v = cntA[e * 128 + tid]; s[tid] = v; }
        if (tid < 128) rd[tid] = sumA[e * 128 + tid];
        __syncthreads();
        for (int o = 1; o < 128; o <<= 1) {
            int add = 0;
            if (tid < 128 && tid >= o) add = s[tid - o];
            __syncthreads();
            if (tid < 128) s[tid] += add;
            __syncthreads();
        }
        if (tid < 128) baseA[e * 128 + tid] = s[tid] - v;
        if (tid == 127) { rawc[e] = s[127]; cnt[e] = (s[127] < CAPC) ? s[127] : CAPC; }
        for (int o = 64; o > 0; o >>= 1) {
            if (tid < o) rd[tid] += rd[tid + o];
            __syncthreads();
        }
        if (tid == 0) ps[e] = rd[0];
        __syncthreads();
    }
    if (tid == 0) {
        double acc = 0.0;
        for (int e = 0; e < 7; ++e) acc += ps[e] * (double)rawc[e];
        out[(long)NTOK * DDIM] = (float)(7.0 * acc / (8192.0 * 8192.0));
    }
}

// ---------------- phase C: slot assignment (FCFS, capacity-dropped) ----------------
__global__ void k_assign(const int* __restrict__ idx0, const int* __restrict__ idx1,
                         const int* __restrict__ baseA, int* __restrict__ slot_token,
                         int* __restrict__ ts0, int* __restrict__ ts1) {
    int lane = threadIdx.x & 63;
    int chunk = (blockIdx.x * 256 + threadIdx.x) >> 6;
    int t = chunk * 64 + lane;
    int i0 = idx0[t], i1 = idx1[t];
    int myts0 = -1, myts1 = -1;
    unsigned long long lt = (1ull << lane) - 1ull;
#pragma unroll
    for (int e = 0; e < 7; ++e) {
        bool has = (i0 == e) || (i1 == e);
        unsigned long long m = __ballot(has);
        int pre = __popcll(m & lt);
        int pos = baseA[e * 128 + chunk] + pre;
        if (has && pos < CAPC) {
            int slot = e * CPAD + pos;
            slot_token[slot] = t;
            if (i0 == e) myts0 = slot; else myts1 = slot;
        }
    }
    ts0[t] = myts0; ts1[t] = myts1;
}

// ---------------- fused MFMA GEMM: experts (blocks 0..1175) + shared (1176..1687) ----------------
// 128x128 tile, BK=64, global_load_lds width-16 staging (m97 pattern).
template <bool GATHER, bool MODE_H>
__global__ __launch_bounds__(256) void k_gemm(
    const u16* __restrict__ AbaseE, const u16* __restrict__ AbaseS,
    const int* __restrict__ gidx, const u16* __restrict__ zrow,
    const u16* __restrict__ WtE, const u16* __restrict__ WtS,
    const float* __restrict__ biasE, const float* __restrict__ biasS,
    u16* __restrict__ outE, u16* __restrict__ outS,
    const int* __restrict__ cnt) {
    __shared__ __align__(16) u16 ldsA[128 * 64];
    __shared__ __align__(16) u16 ldsB[128 * 64];
    int bid = blockIdx.x;
    int tid = threadIdx.x, lane = tid & 63, wv = tid >> 6;
    int lrow = lane >> 3, lkg = lane & 7;
    int kgs = lkg ^ lrow;

    int e = 0, my, nx;
    const u16* Ab; const u16* Bb; const float* bias; u16* outp;
    bool gather = false;
    if (bid < EBLK) {
        e = bid / 168; int r = bid % 168; my = r >> 3; nx = r & 7;
        if (my * 128 >= cnt[e]) return;
        Ab = AbaseE + (GATHER ? 0L : (long)e * CPAD * 1024);
        Bb = WtE + ((long)e << 20);
        bias = biasE + e * 1024;
        outp = outE + (long)e * CPAD * 1024;
        gather = GATHER;
    } else {
        int sb = bid - EBLK; my = sb >> 3; nx = sb & 7;
        Ab = AbaseS; Bb = WtS; bias = biasS; outp = outS;
    }
    int m0 = my * 128, n0 = nx * 128;

    const u16* arow[4];
    const u16* brow[4];
#pragma unroll
    for (int i = 0; i < 4; ++i) {
        int r = (wv * 4 + i) * 8 + lrow;     // 0..127
        if (gather) {
            int tok = gidx[e * CPAD + m0 + r];
            arow[i] = (tok < NTOK) ? (AbaseE + (long)tok * DDIM) : zrow;
        } else {
            arow[i] = Ab + (long)(m0 + r) * DDIM;
        }
        brow[i] = Bb + (long)(n0 + r) * DDIM;
    }
    f32x4 acc[4][4];
#pragma unroll
    for (int a = 0; a < 4; ++a)
#pragma unroll
        for (int b = 0; b < 4; ++b) { f32x4 z = {0.f, 0.f, 0.f, 0.f}; acc[a][b] = z; }

    int wm = (wv >> 1) * 64, wn = (wv & 1) * 64;
    int rl = lane & 15, quad = lane >> 4;

    for (int k0 = 0; k0 < 1024; k0 += 64) {
#pragma unroll
        for (int i = 0; i < 4; ++i) {
            gl2lds16(arow[i] + k0 + kgs * 8, &ldsA[(wv * 4 + i) * 512]);
            gl2lds16(brow[i] + k0 + kgs * 8, &ldsB[(wv * 4 + i) * 512]);
        }
        __syncthreads();   // drains vmcnt -> staged tile visible
#pragma unroll
        for (int ks = 0; ks < 2; ++ks) {
            int kg = ks * 4 + quad;
            bf16x8 af[4], bf[4];
#pragma unroll
            for (int mi = 0; mi < 4; ++mi) {
                int row = wm + mi * 16 + rl;
                af[mi] = *(const bf16x8*)&ldsA[row * 64 + (kg ^ (row & 7)) * 8];
            }
#pragma unroll
            for (int ni = 0; ni < 4; ++ni) {
                int row = wn + ni * 16 + rl;
                bf[ni] = *(const bf16x8*)&ldsB[row * 64 + (kg ^ (row & 7)) * 8];
            }
#pragma unroll
            for (int mi = 0; mi < 4; ++mi)
#pragma unroll
                for (int ni = 0; ni < 4; ++ni)
                    acc[mi][ni] = __builtin_amdgcn_mfma_f32_16x16x32_bf16(
                        af[mi], bf[ni], acc[mi][ni], 0, 0, 0);
        }
        __syncthreads();   // all reads done before next tile overwrites
    }
    // epilogue: C/D layout col = lane&15, row = quad*4 + reg
#pragma unroll
    for (int ni = 0; ni < 4; ++ni) {
        int col = n0 + wn + ni * 16 + rl;
        float bv = bias[col];
#pragma unroll
        for (int mi = 0; mi < 4; ++mi) {
            int rowb = m0 + wm + mi * 16 + quad * 4;
#pragma unroll
            for (int r = 0; r < 4; ++r) {
                float v = acc[mi][ni][r] + bv;
                if constexpr (MODE_H) v = v > 0.f ? v : 0.f;
                outp[(long)(rowb + r) * DDIM + col] = f2bf(v);
            }
        }
    }
}

// ---------------- combine: out = Xs + g0*OutE[s0] + g1*OutE[s1] ----------------
__global__ __launch_bounds__(256) void k_combine(
    const u16* __restrict__ Xs, const u16* __restrict__ OutE,
    const int* __restrict__ ts0, const int* __restrict__ ts1,
    const float* __restrict__ p0, const float* __restrict__ p1,
    float* __restrict__ out) {
    int b = blockIdx.x;
    int d = threadIdx.x * 4;
    long base = (long)b * DDIM + d;
    ushort4 xs4 = *(const ushort4*)(Xs + base);
    float r0 = bf2f(xs4.x), r1 = bf2f(xs4.y), r2 = bf2f(xs4.z), r3 = bf2f(xs4.w);
    int s0 = ts0[b], s1 = ts1[b];
    if (s0 >= 0) {
        float g = p0[b];
        ushort4 o4 = *(const ushort4*)(OutE + (long)s0 * DDIM + d);
        r0 += g * bf2f(o4.x); r1 += g * bf2f(o4.y); r2 += g * bf2f(o4.z); r3 += g * bf2f(o4.w);
    }
    if (s1 >= 0) {
        float g = p1[b];
        ushort4 o4 = *(const ushort4*)(OutE + (long)s1 * DDIM + d);
        r0 += g * bf2f(o4.x); r1 += g * bf2f(o4.y); r2 += g * bf2f(o4.z); r3 += g * bf2f(o4.w);
    }
    float4 w; w.x = r0; w.y = r1; w.z = r2; w.w = r3;
    *(float4*)(out + base) = w;
}

extern "C" void kernel_launch(void* const* d_in, const int* in_sizes, int n_in,
                              void* d_out, int out_size, void* d_ws, size_t ws_size,
                              hipStream_t stream) {
    const float* x    = (const float*)d_in[0];
    const float* noise= (const float*)d_in[1];
    const float* Wr   = (const float*)d_in[2];
    const float* br   = (const float*)d_in[3];
    const float* Wn   = (const float*)d_in[4];
    const float* bn   = (const float*)d_in[5];
    const float* W1   = (const float*)d_in[6];
    const float* b1   = (const float*)d_in[7];
    const float* W2   = (const float*)d_in[8];
    const float* b2   = (const float*)d_in[9];
    const float* Ws1  = (const float*)d_in[10];
    const float* bs1  = (const float*)d_in[11];
    const float* Ws2  = (const float*)d_in[12];
    const float* bs2  = (const float*)d_in[13];
    float* out = (float*)d_out;
    char* ws = (char*)d_ws;

    size_t off = 0;
    auto alloc = [&](size_t bytes) { size_t o = off; off += (bytes + 255) & ~(size_t)255; return o; };
    u16*  Wt   = (u16*)(ws + alloc(7ull * 1048576 * 2));
    u16*  Wst  = (u16*)(ws + alloc(1048576ull * 2));
    u16*  xb   = (u16*)(ws + alloc((size_t)NTOK * 1024 * 2));
    u16*  He   = (u16*)(ws + alloc((size_t)NEXP * CPAD * 1024 * 2));
    u16*  Hs   = (u16*)(ws + alloc((size_t)NTOK * 1024 * 2));
    u16*  OutE = (u16*)(ws + alloc((size_t)NEXP * CPAD * 1024 * 2));
    u16*  Xs   = (u16*)(ws + alloc((size_t)NTOK * 1024 * 2));
    int*  idx0 = (int*)(ws + alloc(NTOK * 4));
    int*  idx1 = (int*)(ws + alloc(NTOK * 4));
    float* p0  = (float*)(ws + alloc(NTOK * 4));
    float* p1  = (float*)(ws + alloc(NTOK * 4));
    int*  ts0  = (int*)(ws + alloc(NTOK * 4));
    int*  ts1  = (int*)(ws + alloc(NTOK * 4));
    int*  slot_token = (int*)(ws + alloc(NEXP * CPAD * 4));
    int*  cntA = (int*)(ws + alloc(7 * 128 * 4));
    int*  baseA= (int*)(ws + alloc(7 * 128 * 4));
    double* sumA = (double*)(ws + alloc(7 * 128 * 8));
    int*  cnt    = (int*)(ws + alloc(8 * 4));
    u16*  zrow   = (u16*)(ws + alloc(1024 * 2));
    double* arO  = (double*)(ws + alloc((size_t)NTOK * 7 * 8));
    double* anO  = (double*)(ws + alloc((size_t)NTOK * 7 * 8));
    size_t base_off = off;
    // optional separate phase-2 transpose buffers (removes mid-pipeline bubble)
    u16*  Wt2  = (u16*)(ws + alloc(7ull * 1048576 * 2));
    u16*  Wst2 = (u16*)(ws + alloc(1048576ull * 2));

    if (base_off > ws_size) {
        k_zero<<<2048, 256, 0, stream>>>(out, (long)out_size);
        return;
    }
    bool sep = (off <= ws_size);
    if (!sep) { Wt2 = Wt; Wst2 = Wst; }

    // fused: x->bf16 + inits + transpose W1/Ws1 (+ W2/Ws2 when sep)
    k_prep<<<sep ? 12288 : 8192, 256, 0, stream>>>(
        x, xb, slot_token, zrow, W1, Ws1, Wt, Wst, W2, Ws2, Wt2, Wst2);
    k_router<<<1024, 512, 0, stream>>>(x, Wr, Wn, arO, anO);
    k_tail<<<32, 256, 0, stream>>>(arO, anO, noise, br, bn, idx0, idx1, p0, p1, cntA, sumA);
    k_scanbase<<<1, 256, 0, stream>>>(cntA, sumA, baseA, cnt, out);
    k_assign<<<32, 256, 0, stream>>>(idx0, idx1, baseA, slot_token, ts0, ts1);

    // fused layer 1: experts (gather xb via slot_token) + shared, relu -> bf16 He/Hs
    k_gemm<true, true><<<TBLK, 256, 0, stream>>>(
        xb, xb, slot_token, zrow, Wt, Wst, b1, bs1, He, Hs, cnt);

    if (!sep)   // fallback: in-place phase-2 transpose between the GEMMs
        k_transpose<<<dim3(4, 128, 8), 256, 0, stream>>>(W2, Ws2, Wt, Wst);

    // fused layer 2: -> bf16 OutE/Xs (+b2/bs2)
    k_gemm<false, false><<<TBLK, 256, 0, stream>>>(
        He, Hs, nullptr, zrow, Wt2, Wst2, b2, bs2, OutE, Xs, cnt);

    k_combine<<<NTOK, 256, 0, stream>>>(Xs, OutE, ts0, ts1, p0, p1, out);
    (void)in_sizes; (void)n_in; (void)out_size;
}